// Round 5
// baseline (200.351 us; speedup 1.0000x reference)
//
#include <hip/hip_runtime.h>
#include <math.h>

// Problem constants (B,C,H,W = 8,256,64,64; N = H*W = 4096)
#define BQ 8
#define CQ 256
#define NQ 4096
#define MT 128          // m-tile per block
#define NSTEP (NQ / 32) // 128 K-chunks of 32

typedef short s16x8 __attribute__((ext_vector_type(8)));
typedef short s16x4 __attribute__((ext_vector_type(4)));
typedef float f32x4 __attribute__((ext_vector_type(4)));

static __device__ __forceinline__ float4 ld4(const float* p) { return *(const float4*)p; }

static constexpr float LOG2E = 1.4426950408889634f;

static __device__ __forceinline__ short f2bf(float f) {
    return __builtin_bit_cast(short, (__bf16)f);
}

// -------- K1: f' = (wq.x)*log2e, g = wk.x, xbf = bf16(x) --------
__global__ void k_fg(const float* __restrict__ x, const float* __restrict__ wq,
                     const float* __restrict__ wk, float* __restrict__ fs,
                     float* __restrict__ g, short* __restrict__ xbf) {
    int b = blockIdx.y;
    int nloc = threadIdx.x & 63;
    int cg = threadIdx.x >> 6;           // 0..3 c-group
    int n = blockIdx.x * 64 + nloc;
    const float* xb = x + (size_t)b * CQ * NQ + n;
    short* xo = xbf + (size_t)b * CQ * NQ + n;
    float accf = 0.f, accg = 0.f;
    int c0 = cg * 64;
#pragma unroll 8
    for (int c = c0; c < c0 + 64; ++c) {
        float v = xb[(size_t)c * NQ];
        accf = fmaf(wq[c], v, accf);
        accg = fmaf(wk[c], v, accg);
        xo[(size_t)c * NQ] = f2bf(v);
    }
    __shared__ float sf[4][64], sg2[4][64];
    sf[cg][nloc] = accf;
    sg2[cg][nloc] = accg;
    __syncthreads();
    if (threadIdx.x < 64) {
        float f = sf[0][nloc] + sf[1][nloc] + sf[2][nloc] + sf[3][nloc];
        float gg = sg2[0][nloc] + sg2[1][nloc] + sg2[2][nloc] + sg2[3][nloc];
        fs[b * NQ + blockIdx.x * 64 + nloc] = f * LOG2E;
        g[b * NQ + blockIdx.x * 64 + nloc] = gg;
    }
}

// -------- K1b: per-batch max/min of f' --------
__global__ void k_minmax(const float* __restrict__ fs, float* __restrict__ fmx,
                         float* __restrict__ fmn) {
    int b = blockIdx.x;
    const float* f = fs + b * NQ;
    float mx = -1e30f, mn = 1e30f;
    for (int i = threadIdx.x; i < NQ; i += 256) {
        float v = f[i];
        mx = fmaxf(mx, v);
        mn = fminf(mn, v);
    }
    for (int off = 32; off; off >>= 1) {
        mx = fmaxf(mx, __shfl_down(mx, off));
        mn = fminf(mn, __shfl_down(mn, off));
    }
    __shared__ float smx[4], smn[4];
    int wid = threadIdx.x >> 6;
    if ((threadIdx.x & 63) == 0) { smx[wid] = mx; smn[wid] = mn; }
    __syncthreads();
    if (threadIdx.x == 0) {
        mx = fmaxf(fmaxf(smx[0], smx[1]), fmaxf(smx[2], smx[3]));
        mn = fminf(fminf(smn[0], smn[1]), fminf(smn[2], smn[3]));
        fmx[b] = mx;
        fmn[b] = mn;
    }
}

// LDS map (byte offsets):
//   [0, 64K)       : 4-deep stage ring, 16KB slots (256c x 32n bf16); later merge + y_lds
//   [64K, 128K)    : merge region upper half (with ring: 4 pairs x 32KB f32 partials)
//   [128K, 144K)   : f_lds (4096 f32)
//   [144K, 146K)   : zbuf
#define RING_OFF 0
#define FLDS_OFF 131072
#define ZBUF_OFF 147456
#define SMEM_BYTES 149504

// -------- K2 fused: y[c][m] = sum_n x[c][n] e[n,m];  o = (1-g)*wv*(y/Z) + g*x --------
// 512 thr, 8 waves: w = wc*4 + wm*2 + ws. Block tile 256c x 128m.
// Wave tile 128c x 64m (jc=8 x jm=4), 2-way n-split (ws = K-chunk parity).
// 4-deep ring + counted vmcnt(4) + raw s_barrier: loads in flight across barriers.
__global__ void __launch_bounds__(512, 2) k_attn(
    const short* __restrict__ xbf, const float* __restrict__ fsp,
    const float* __restrict__ gp, const float* __restrict__ fmxs,
    const float* __restrict__ fmns, const float* __restrict__ wv,
    const float* __restrict__ x, const float* __restrict__ gamma,
    float* __restrict__ out) {
    __shared__ __align__(16) char smem[SMEM_BYTES];

    int bid = blockIdx.x;
    int b = bid & 7;            // batch -> XCD affinity (2MB xbf slice per XCD L2)
    int mblk = bid >> 3;        // 0..31
    int m0 = mblk * MT;
    int tid = threadIdx.x;
    int l = tid & 63;
    int w = tid >> 6;           // 0..7
    int ws = w & 1;             // n-parity
    int wm = (w >> 1) & 1;      // m-half
    int wc = w >> 2;            // c-half
    int q = l >> 4;             // k-slot
    int cr = l & 15;            // A-row / B-col within frag

    const short* xb = xbf + (size_t)b * CQ * NQ;
    const float* fb = fsp + b * NQ;

    // ---- prolog staging: f (2 loads), then ring chunks 0,1,2 (6 loads) ----
#pragma unroll
    for (int r2 = 0; r2 < 2; ++r2) {
        int off = tid * 16 + r2 * 8192;
        __builtin_amdgcn_global_load_lds(
            (const __attribute__((address_space(1))) void*)(fb + (off >> 2)),
            (__attribute__((address_space(3))) void*)(smem + FLDS_OFF + off), 16, 0, 0);
    }
#pragma unroll
    for (int c3 = 0; c3 < 3; ++c3) {
#pragma unroll
        for (int r2 = 0; r2 < 2; ++r2) {
            int off = tid * 16 + r2 * 8192;
            int row = off >> 6, nb = off & 63;
            __builtin_amdgcn_global_load_lds(
                (const __attribute__((address_space(1))) void*)(xb + (size_t)row * NQ + c3 * 32 + (nb >> 1)),
                (__attribute__((address_space(3))) void*)(smem + c3 * 16384 + off), 16, 0, 0);
        }
    }

    float fmx = fmxs[b], fmn = fmns[b];
    const float* gb = gp + b * NQ;
    float gj[4], nM[4], zac[4];
#pragma unroll
    for (int jm = 0; jm < 4; ++jm) {
        float gv = gb[m0 + wm * 64 + jm * 16 + cr];
        gj[jm] = gv;
        nM[jm] = -((gv >= 0.f) ? gv * fmx : gv * fmn);
        zac[jm] = 0.f;
    }

    f32x4 acc[8][4];
#pragma unroll
    for (int jc = 0; jc < 8; ++jc)
#pragma unroll
        for (int jm = 0; jm < 4; ++jm) acc[jc][jm] = (f32x4){0.f, 0.f, 0.f, 0.f};

    for (int t = 0; t < NSTEP; ++t) {
        // own f+chunk(t) loads landed (leaves chunks t+1,t+2 = 4 outstanding);
        // barrier => ALL waves waited => tile t complete; also: everyone done
        // reading slot (t-1)&3, so staging (t+3)->that slot below is safe.
        asm volatile("s_waitcnt vmcnt(4)" ::: "memory");
        __builtin_amdgcn_s_barrier();
        {   // stage chunk (t+3) (wrapped in tail to keep vmcnt counting uniform)
            int chunk = (t + 3) & (NSTEP - 1);
            char* nbuf = smem + ((t + 3) & 3) * 16384;
#pragma unroll
            for (int r2 = 0; r2 < 2; ++r2) {
                int off = tid * 16 + r2 * 8192;
                int row = off >> 6, nb = off & 63;
                __builtin_amdgcn_global_load_lds(
                    (const __attribute__((address_space(1))) void*)(xb + (size_t)row * NQ + chunk * 32 + (nb >> 1)),
                    (__attribute__((address_space(3))) void*)(nbuf + off), 16, 0, 0);
            }
        }
        if ((t & 1) == ws) {   // n-split: this wave computes only its parity
            const char* cbuf = smem + (t & 3) * 16384;
            const float* fls = (const float*)(smem + FLDS_OFF) + t * 32;
            float4 fqa = *(const float4*)(fls + q * 8);
            float4 fqb = *(const float4*)(fls + q * 8 + 4);
            float fq[8] = {fqa.x, fqa.y, fqa.z, fqa.w, fqb.x, fqb.y, fqb.z, fqb.w};
            s16x8 bv[4];
#pragma unroll
            for (int jm = 0; jm < 4; ++jm) {
                float z = zac[jm];
#pragma unroll
                for (int i = 0; i < 8; ++i) {
                    float e = __builtin_amdgcn_exp2f(fmaf(fq[i], gj[jm], nM[jm]));
                    z += e;
                    bv[jm][i] = f2bf(e);
                }
                zac[jm] = z;
            }
#pragma unroll
            for (int jc = 0; jc < 8; ++jc) {
                s16x8 av = *(const s16x8*)(cbuf + (wc * 128 + jc * 16 + cr) * 64 + q * 16);
#pragma unroll
                for (int jm = 0; jm < 4; ++jm)
                    acc[jc][jm] = __builtin_amdgcn_mfma_f32_16x16x32_bf16(av, bv[jm], acc[jc][jm], 0, 0, 0);
            }
        }
    }
    __syncthreads();   // full drain (incl. wrap stages)

    // ---- Z: butterfly over k-slots, then exchange across ws-partner ----
    float zf[4];
#pragma unroll
    for (int jm = 0; jm < 4; ++jm) {
        float z = zac[jm];
        z += __shfl_xor(z, 16);
        z += __shfl_xor(z, 32);
        zf[jm] = z;
    }
    float* zb = (float*)(smem + ZBUF_OFF);
    if (q == 0) {
#pragma unroll
        for (int jm = 0; jm < 4; ++jm) zb[w * 64 + jm * 16 + cr] = zf[jm];
    }
    __syncthreads();
#pragma unroll
    for (int jm = 0; jm < 4; ++jm) zf[jm] += zb[(w ^ 1) * 64 + jm * 16 + cr];

    // ---- acc merge: ws1 -> LDS (f32), ws0 adds ----
    {
        int p = wc * 2 + wm;
        float* mrg = (float*)(smem + p * 32768);
        if (ws == 1) {
#pragma unroll
            for (int jc = 0; jc < 8; ++jc)
#pragma unroll
                for (int jm = 0; jm < 4; ++jm)
                    *(f32x4*)(mrg + ((jc * 4 + jm) * 64 + l) * 4) = acc[jc][jm];
        }
        __syncthreads();
        if (ws == 0) {
#pragma unroll
            for (int jc = 0; jc < 8; ++jc)
#pragma unroll
                for (int jm = 0; jm < 4; ++jm) {
                    f32x4 o = *(const f32x4*)(mrg + ((jc * 4 + jm) * 64 + l) * 4);
                    acc[jc][jm] += o;
                }
        }
        __syncthreads();
    }

    // ---- y_norm -> LDS (ws0 waves): y_lds[m][c] bf16, 512B rows, XOR-swizzled ----
    if (ws == 0) {
        float rzl[4];
#pragma unroll
        for (int jm = 0; jm < 4; ++jm) rzl[jm] = 1.0f / zf[jm];
#pragma unroll
        for (int jc = 0; jc < 8; ++jc) {
#pragma unroll
            for (int jm = 0; jm < 4; ++jm) {
                int mloc = wm * 64 + jm * 16 + cr;
                int cb = (wc * 256 + jc * 32 + q * 8) ^ ((mloc & 7) << 4);
                s16x4 v;
#pragma unroll
                for (int r = 0; r < 4; ++r) v[r] = f2bf(acc[jc][jm][r] * rzl[jm]);
                *(s16x4*)(smem + mloc * 512 + cb) = v;
            }
        }
    }
    __syncthreads();

    // ---- GEMM2: o[c_out][m] = wv[c_out][:] . y_norm[:][m], K=256 (all 8 waves) ----
    int co0 = w * 32;
    f32x4 acc2[2][8];
#pragma unroll
    for (int j2 = 0; j2 < 2; ++j2)
#pragma unroll
        for (int jm2 = 0; jm2 < 8; ++jm2) acc2[j2][jm2] = (f32x4){0.f, 0.f, 0.f, 0.f};

#pragma unroll 2
    for (int ks = 0; ks < 8; ++ks) {
        s16x8 a2[2];
#pragma unroll
        for (int j2 = 0; j2 < 2; ++j2) {
            const float* wr = wv + (size_t)(co0 + j2 * 16 + cr) * CQ + ks * 32 + q * 8;
            float4 wa = ld4(wr);
            float4 wb = ld4(wr + 4);
            a2[j2][0] = f2bf(wa.x); a2[j2][1] = f2bf(wa.y);
            a2[j2][2] = f2bf(wa.z); a2[j2][3] = f2bf(wa.w);
            a2[j2][4] = f2bf(wb.x); a2[j2][5] = f2bf(wb.y);
            a2[j2][6] = f2bf(wb.z); a2[j2][7] = f2bf(wb.w);
        }
#pragma unroll
        for (int jm2 = 0; jm2 < 8; ++jm2) {
            int mloc = jm2 * 16 + cr;
            s16x8 b2 = *(const s16x8*)(smem + mloc * 512 + ((ks * 64 + q * 16) ^ ((mloc & 7) << 4)));
#pragma unroll
            for (int j2 = 0; j2 < 2; ++j2)
                acc2[j2][jm2] = __builtin_amdgcn_mfma_f32_16x16x32_bf16(a2[j2], b2, acc2[j2][jm2], 0, 0, 0);
        }
    }

    // ---- epilogue ----
    float gam = gamma[0];
    float omg = 1.f - gam;
    if (gam != 0.f) {
#pragma unroll
        for (int j2 = 0; j2 < 2; ++j2)
#pragma unroll
            for (int jm2 = 0; jm2 < 8; ++jm2)
#pragma unroll
                for (int r = 0; r < 4; ++r) {
                    int c_out = co0 + j2 * 16 + q * 4 + r;
                    size_t idx = ((size_t)b * CQ + c_out) * NQ + m0 + jm2 * 16 + cr;
                    __builtin_nontemporal_store(
                        fmaf(gam, x[idx], acc2[j2][jm2][r] * omg), out + idx);
                }
    } else {
#pragma unroll
        for (int j2 = 0; j2 < 2; ++j2)
#pragma unroll
            for (int jm2 = 0; jm2 < 8; ++jm2)
#pragma unroll
                for (int r = 0; r < 4; ++r) {
                    int c_out = co0 + j2 * 16 + q * 4 + r;
                    size_t idx = ((size_t)b * CQ + c_out) * NQ + m0 + jm2 * 16 + cr;
                    __builtin_nontemporal_store(acc2[j2][jm2][r] * omg, out + idx);
                }
    }
}

extern "C" void kernel_launch(void* const* d_in, const int* in_sizes, int n_in,
                              void* d_out, int out_size, void* d_ws, size_t ws_size,
                              hipStream_t stream) {
    const float* x     = (const float*)d_in[0];
    const float* wq    = (const float*)d_in[1];
    const float* wk    = (const float*)d_in[2];
    const float* wv    = (const float*)d_in[3];
    const float* gamma = (const float*)d_in[4];
    float* out = (float*)d_out;

    // ws (floats): fs[B*N] | g[B*N] | fmx[B] | fmn[B] | pad -> xbf (bf16) [B*C*N]
    float* ws  = (float*)d_ws;
    float* fs  = ws;
    float* g   = ws + BQ * NQ;
    float* fmx = ws + 2 * BQ * NQ;
    float* fmn = fmx + BQ;
    short* xbf = (short*)(ws + 2 * BQ * NQ + 64);

    hipLaunchKernelGGL(k_fg, dim3(NQ / 64, BQ), dim3(256), 0, stream, x, wq, wk, fs, g, xbf);
    hipLaunchKernelGGL(k_minmax, dim3(BQ), dim3(256), 0, stream, fs, fmx, fmn);
    hipLaunchKernelGGL(k_attn, dim3(BQ * (NQ / MT)), dim3(512), 0, stream,
                       xbf, fs, g, fmx, fmn, wv, x, gamma, out);
}

// Round 6
// 119.775 us; speedup vs baseline: 1.6727x; 1.6727x over previous
//
#include <hip/hip_runtime.h>
#include <math.h>

// Problem constants (B,C,H,W = 8,256,64,64; N = H*W = 4096)
#define BQ 8
#define CQ 256
#define NQ 4096
#define MT 128            // m-tile per block
#define NSUP 64           // supersteps (2 chunks of 32n each)

typedef short s16x8 __attribute__((ext_vector_type(8)));
typedef short s16x4 __attribute__((ext_vector_type(4)));
typedef float f32x4 __attribute__((ext_vector_type(4)));
typedef unsigned int uint;

static __device__ __forceinline__ float4 ld4(const float* p) { return *(const float4*)p; }

static constexpr float LOG2E = 1.4426950408889634f;

static __device__ __forceinline__ short f2bf(float f) {
    return __builtin_bit_cast(short, (__bf16)f);
}
// monotonic uint key for float compare via atomicMax/Min
static __device__ __forceinline__ uint fkey(float f) {
    uint b = __builtin_bit_cast(uint, f);
    return b ^ (0x80000000u | (uint)((int)b >> 31));
}
static __device__ __forceinline__ float fdec(uint u) {
    uint b = (u & 0x80000000u) ? (u ^ 0x80000000u) : ~u;
    return __builtin_bit_cast(float, b);
}

// -------- K1: f' = (wq.x)*log2e, g = wk.x, xbf = bf16(x), fused batch max/min --------
// grid (NQ/64, BQ) x 256 thr; 8-way c-split, 2n per thread (float2 loads).
__global__ void k_fg(const float* __restrict__ x, const float* __restrict__ wq,
                     const float* __restrict__ wk, float* __restrict__ fs,
                     float* __restrict__ g, short* __restrict__ xbf,
                     uint* __restrict__ fmxu, uint* __restrict__ fmnu) {
    int b = blockIdx.y;
    int t = threadIdx.x;
    int nl = (t & 31) * 2;
    int cg = t >> 5;                     // 0..7
    int n = blockIdx.x * 64 + nl;
    const float* xb = x + (size_t)b * CQ * NQ + n;
    uint* xo = (uint*)(xbf + (size_t)b * CQ * NQ + n);
    float f0 = 0.f, f1 = 0.f, g0 = 0.f, g1 = 0.f;
    int c0 = cg * 32;
#pragma unroll 8
    for (int c = c0; c < c0 + 32; ++c) {
        float2 v = *(const float2*)&xb[(size_t)c * NQ];
        f0 = fmaf(wq[c], v.x, f0);
        f1 = fmaf(wq[c], v.y, f1);
        g0 = fmaf(wk[c], v.x, g0);
        g1 = fmaf(wk[c], v.y, g1);
        uint p = (uint)(unsigned short)f2bf(v.x) | ((uint)(unsigned short)f2bf(v.y) << 16);
        xo[c * (NQ / 2)] = p;
    }
    __shared__ float sf[8][64], sg2[8][64];
    sf[cg][nl] = f0;  sf[cg][nl + 1] = f1;
    sg2[cg][nl] = g0; sg2[cg][nl + 1] = g1;
    __syncthreads();
    if (t < 64) {
        float f = 0.f, gg = 0.f;
#pragma unroll
        for (int i = 0; i < 8; ++i) { f += sf[i][t]; gg += sg2[i][t]; }
        f *= LOG2E;
        fs[b * NQ + blockIdx.x * 64 + t] = f;
        g[b * NQ + blockIdx.x * 64 + t]  = gg;
        float mx = f, mn = f;
#pragma unroll
        for (int off = 32; off; off >>= 1) {
            mx = fmaxf(mx, __shfl_xor(mx, off));
            mn = fminf(mn, __shfl_xor(mn, off));
        }
        if (t == 0) {
            atomicMax(&fmxu[b], fkey(mx));
            atomicMin(&fmnu[b], fkey(mn));
        }
    }
}

// LDS map (bytes):
//   [0, 64K)      : two 32KB pair-buffers (each = 2 chunks of 256c x 32n bf16, q-swizzled)
//   [0, 128K)     : post-loop f32 partial-merge region (4 pairs x 32KB)
//   [0, 64K)      : post-merge y_lds (128m x 512B, XOR-swizzled)
//   [128K, 144K)  : f_lds (4096 f32)
//   [144K, 146K)  : zbuf
#define FLDS_OFF 131072
#define ZBUF_OFF 147456
#define SMEM_BYTES 149504

// stage one 32KB pair (chunks 2*pi, 2*pi+1) with q-swizzle pre-applied on the
// GLOBAL source (LDS dest stays linear — global_load_lds requirement)
#define STAGE_PAIR(bufp, pi)                                                       \
    {                                                                              \
        int cpair2_ = (pi) * 2;                                                    \
        _Pragma("unroll")                                                          \
        for (int r2_ = 0; r2_ < 4; ++r2_) {                                        \
            int off_ = tid * 16 + r2_ * 8192;                                      \
            int half_ = off_ >> 14;                                                \
            int rem_ = off_ & 16383;                                               \
            int row_ = rem_ >> 6;                                                  \
            int lq_ = ((rem_ >> 4) & 3) ^ ((row_ >> 1) & 3);                       \
            const short* src_ = xb + (size_t)row_ * NQ + (cpair2_ + half_) * 32 + lq_ * 8; \
            __builtin_amdgcn_global_load_lds(                                      \
                (const __attribute__((address_space(1))) void*)src_,               \
                (__attribute__((address_space(3))) void*)((bufp) + off_), 16, 0, 0); \
        }                                                                          \
    }

// -------- K2 fused: y[c][m] = sum_n x[c][n] e[n,m];  o = (1-g)*wv*(y/Z) + g*x --------
// 512 thr, 8 waves: ws = w&1 (chunk-in-pair), wm = (w>>1)&1 (m-half), wc = w>>2 (c-half).
// Block tile 256c x 128m; wave tile 128c x 64m (jc=8 x jm=4). Superstep = 2 chunks:
// ALL waves compute every phase; one __syncthreads per superstep; 32KB pair prefetch.
__global__ void __launch_bounds__(512, 1) k_attn(
    const short* __restrict__ xbf, const float* __restrict__ fsp,
    const float* __restrict__ gp, const uint* __restrict__ fmxu,
    const uint* __restrict__ fmnu, const float* __restrict__ wv,
    const float* __restrict__ x, const float* __restrict__ gamma,
    float* __restrict__ out) {
    __shared__ __align__(16) char smem[SMEM_BYTES];

    int bid = blockIdx.x;
    int b = bid & 7;            // batch -> XCD affinity (2MB xbf slice per XCD L2)
    int mblk = bid >> 3;        // 0..31
    int m0 = mblk * MT;
    int tid = threadIdx.x;
    int l = tid & 63;
    int w = tid >> 6;           // 0..7
    int ws = w & 1;             // chunk within pair
    int wm = (w >> 1) & 1;      // m-half
    int wc = w >> 2;            // c-half
    int q = l >> 4;             // k-slot
    int cr = l & 15;            // A-row / B-col within frag
    int qp16 = (q ^ ((cr >> 1) & 3)) * 16;   // swizzled 16B slot for A-reads

    const short* xb = xbf + (size_t)b * CQ * NQ;
    const float* fb = fsp + b * NQ;

    // ---- prolog: stage f (16KB) + pair 0 ----
#pragma unroll
    for (int r2 = 0; r2 < 2; ++r2) {
        int off = tid * 16 + r2 * 8192;
        __builtin_amdgcn_global_load_lds(
            (const __attribute__((address_space(1))) void*)(fb + (off >> 2)),
            (__attribute__((address_space(3))) void*)(smem + FLDS_OFF + off), 16, 0, 0);
    }
    STAGE_PAIR(smem, 0)

    float fmx = fdec(fmxu[b]), fmn = fdec(fmnu[b]);
    const float* gb = gp + b * NQ;
    float gj[4], nM[4], zac[4];
#pragma unroll
    for (int jm = 0; jm < 4; ++jm) {
        float gv = gb[m0 + wm * 64 + jm * 16 + cr];
        gj[jm] = gv;
        nM[jm] = -((gv >= 0.f) ? gv * fmx : gv * fmn);
        zac[jm] = 0.f;
    }

    f32x4 acc[8][4];
#pragma unroll
    for (int jc = 0; jc < 8; ++jc)
#pragma unroll
        for (int jm = 0; jm < 4; ++jm) acc[jc][jm] = (f32x4){0.f, 0.f, 0.f, 0.f};

    __syncthreads();   // f + pair0 ready

    for (int s = 0; s < NSUP; ++s) {
        char* nbuf = smem + ((s & 1) ^ 1) * 32768;
        if (s < NSUP - 1) STAGE_PAIR(nbuf, s + 1)   // lands during compute below

        int chunk = 2 * s + ws;
        const char* cbuf = smem + (s & 1) * 32768 + ws * 16384;
        const float* fls = (const float*)(smem + FLDS_OFF) + chunk * 32;
        float4 fqa = *(const float4*)(fls + q * 8);
        float4 fqb = *(const float4*)(fls + q * 8 + 4);
        float fq[8] = {fqa.x, fqa.y, fqa.z, fqa.w, fqb.x, fqb.y, fqb.z, fqb.w};
        s16x8 bv[4];
#pragma unroll
        for (int jm = 0; jm < 4; ++jm) {
            float z = zac[jm];
#pragma unroll
            for (int i = 0; i < 8; ++i) {
                float e = __builtin_amdgcn_exp2f(fmaf(fq[i], gj[jm], nM[jm]));
                z += e;
                bv[jm][i] = f2bf(e);
            }
            zac[jm] = z;
        }
#pragma unroll
        for (int jc = 0; jc < 8; ++jc) {
            s16x8 av = *(const s16x8*)(cbuf + (wc * 128 + jc * 16 + cr) * 64 + qp16);
#pragma unroll
            for (int jm = 0; jm < 4; ++jm)
                acc[jc][jm] = __builtin_amdgcn_mfma_f32_16x16x32_bf16(av, bv[jm], acc[jc][jm], 0, 0, 0);
        }
        __syncthreads();   // pair s+1 landed; everyone done with buf (s&1)
    }

    // ---- Z: butterfly over k-slots, then exchange across ws-partner ----
    float zf[4];
#pragma unroll
    for (int jm = 0; jm < 4; ++jm) {
        float z = zac[jm];
        z += __shfl_xor(z, 16);
        z += __shfl_xor(z, 32);
        zf[jm] = z;
    }
    float* zb = (float*)(smem + ZBUF_OFF);
    if (q == 0) {
#pragma unroll
        for (int jm = 0; jm < 4; ++jm) zb[w * 64 + jm * 16 + cr] = zf[jm];
    }
    __syncthreads();
#pragma unroll
    for (int jm = 0; jm < 4; ++jm) zf[jm] += zb[(w ^ 1) * 64 + jm * 16 + cr];

    // ---- acc merge across ws pairs: ws1 -> LDS (f32), ws0 adds ----
    {
        int p = wc * 2 + wm;
        float* mrg = (float*)(smem + p * 32768);
        if (ws == 1) {
#pragma unroll
            for (int jc = 0; jc < 8; ++jc)
#pragma unroll
                for (int jm = 0; jm < 4; ++jm)
                    *(f32x4*)(mrg + ((jc * 4 + jm) * 64 + l) * 4) = acc[jc][jm];
        }
        __syncthreads();
        if (ws == 0) {
#pragma unroll
            for (int jc = 0; jc < 8; ++jc)
#pragma unroll
                for (int jm = 0; jm < 4; ++jm) {
                    f32x4 o = *(const f32x4*)(mrg + ((jc * 4 + jm) * 64 + l) * 4);
                    acc[jc][jm] += o;
                }
        }
        __syncthreads();
    }

    // ---- y_norm -> LDS (ws0 waves): y_lds[m][c] bf16, 512B rows, XOR-swizzled ----
    if (ws == 0) {
        float rzl[4];
#pragma unroll
        for (int jm = 0; jm < 4; ++jm) rzl[jm] = 1.0f / zf[jm];
#pragma unroll
        for (int jc = 0; jc < 8; ++jc) {
#pragma unroll
            for (int jm = 0; jm < 4; ++jm) {
                int mloc = wm * 64 + jm * 16 + cr;
                int cb = (wc * 256 + jc * 32 + q * 8) ^ ((mloc & 7) << 4);
                s16x4 v;
#pragma unroll
                for (int r = 0; r < 4; ++r) v[r] = f2bf(acc[jc][jm][r] * rzl[jm]);
                *(s16x4*)(smem + mloc * 512 + cb) = v;
            }
        }
    }
    __syncthreads();

    // ---- GEMM2: o[c_out][m] = wv[c_out][:] . y_norm[:][m], K=256 (all 8 waves) ----
    int co0 = w * 32;
    f32x4 acc2[2][8];
#pragma unroll
    for (int j2 = 0; j2 < 2; ++j2)
#pragma unroll
        for (int jm2 = 0; jm2 < 8; ++jm2) acc2[j2][jm2] = (f32x4){0.f, 0.f, 0.f, 0.f};

#pragma unroll 2
    for (int ks = 0; ks < 8; ++ks) {
        s16x8 a2[2];
#pragma unroll
        for (int j2 = 0; j2 < 2; ++j2) {
            const float* wr = wv + (size_t)(co0 + j2 * 16 + cr) * CQ + ks * 32 + q * 8;
            float4 wa = ld4(wr);
            float4 wb = ld4(wr + 4);
            a2[j2][0] = f2bf(wa.x); a2[j2][1] = f2bf(wa.y);
            a2[j2][2] = f2bf(wa.z); a2[j2][3] = f2bf(wa.w);
            a2[j2][4] = f2bf(wb.x); a2[j2][5] = f2bf(wb.y);
            a2[j2][6] = f2bf(wb.z); a2[j2][7] = f2bf(wb.w);
        }
#pragma unroll
        for (int jm2 = 0; jm2 < 8; ++jm2) {
            int mloc = jm2 * 16 + cr;
            s16x8 b2 = *(const s16x8*)(smem + mloc * 512 + ((ks * 64 + q * 16) ^ ((mloc & 7) << 4)));
#pragma unroll
            for (int j2 = 0; j2 < 2; ++j2)
                acc2[j2][jm2] = __builtin_amdgcn_mfma_f32_16x16x32_bf16(a2[j2], b2, acc2[j2][jm2], 0, 0, 0);
        }
    }

    // ---- epilogue ----
    float gam = gamma[0];
    float omg = 1.f - gam;
    if (gam != 0.f) {
#pragma unroll
        for (int j2 = 0; j2 < 2; ++j2)
#pragma unroll
            for (int jm2 = 0; jm2 < 8; ++jm2)
#pragma unroll
                for (int r = 0; r < 4; ++r) {
                    int c_out = co0 + j2 * 16 + q * 4 + r;
                    size_t idx = ((size_t)b * CQ + c_out) * NQ + m0 + jm2 * 16 + cr;
                    __builtin_nontemporal_store(
                        fmaf(gam, x[idx], acc2[j2][jm2][r] * omg), out + idx);
                }
    } else {
#pragma unroll
        for (int j2 = 0; j2 < 2; ++j2)
#pragma unroll
            for (int jm2 = 0; jm2 < 8; ++jm2)
#pragma unroll
                for (int r = 0; r < 4; ++r) {
                    int c_out = co0 + j2 * 16 + q * 4 + r;
                    size_t idx = ((size_t)b * CQ + c_out) * NQ + m0 + jm2 * 16 + cr;
                    __builtin_nontemporal_store(acc2[j2][jm2][r] * omg, out + idx);
                }
    }
}

extern "C" void kernel_launch(void* const* d_in, const int* in_sizes, int n_in,
                              void* d_out, int out_size, void* d_ws, size_t ws_size,
                              hipStream_t stream) {
    const float* x     = (const float*)d_in[0];
    const float* wq    = (const float*)d_in[1];
    const float* wk    = (const float*)d_in[2];
    const float* wv    = (const float*)d_in[3];
    const float* gamma = (const float*)d_in[4];
    float* out = (float*)d_out;

    // ws (floats): fs[B*N] | g[B*N] | fmxu[8]+fmnu[8] (uint) | pad -> xbf (bf16) [B*C*N]
    float* ws  = (float*)d_ws;
    float* fs  = ws;
    float* g   = ws + BQ * NQ;
    uint* fmxu = (uint*)(ws + 2 * BQ * NQ);
    uint* fmnu = fmxu + 8;
    short* xbf = (short*)(ws + 2 * BQ * NQ + 64);

    hipMemsetAsync(fmxu, 0x00, 32, stream);   // lowest key
    hipMemsetAsync(fmnu, 0xFF, 32, stream);   // highest key
    hipLaunchKernelGGL(k_fg, dim3(NQ / 64, BQ), dim3(256), 0, stream,
                       x, wq, wk, fs, g, xbf, fmxu, fmnu);
    hipLaunchKernelGGL(k_attn, dim3(BQ * (NQ / MT)), dim3(512), 0, stream,
                       xbf, fs, g, fmxu, fmnu, wv, x, gamma, out);
}

// Round 7
// 117.302 us; speedup vs baseline: 1.7080x; 1.0211x over previous
//
#include <hip/hip_runtime.h>
#include <math.h>

// Problem constants (B,C,H,W = 8,256,64,64; N = H*W = 4096)
#define BQ 8
#define CQ 256
#define NQ 4096
#define MT 128            // m-tile per block
#define NSUP 64           // supersteps (2 chunks of 32n each)

typedef short s16x8 __attribute__((ext_vector_type(8)));
typedef short s16x4 __attribute__((ext_vector_type(4)));
typedef float f32x4 __attribute__((ext_vector_type(4)));
typedef unsigned int uint;

static __device__ __forceinline__ float4 ld4(const float* p) { return *(const float4*)p; }

static constexpr float LOG2E = 1.4426950408889634f;

static __device__ __forceinline__ short f2bf(float f) {
    return __builtin_bit_cast(short, (__bf16)f);
}
// monotonic uint key for float compare via atomicMax/Min
static __device__ __forceinline__ uint fkey(float f) {
    uint b = __builtin_bit_cast(uint, f);
    return b ^ (0x80000000u | (uint)((int)b >> 31));
}
static __device__ __forceinline__ float fdec(uint u) {
    uint b = (u & 0x80000000u) ? (u ^ 0x80000000u) : ~u;
    return __builtin_bit_cast(float, b);
}

// -------- K1: f' = (wq.x)*log2e, g = wk.x, xbf = bf16(x), fused batch max/min --------
__global__ void k_fg(const float* __restrict__ x, const float* __restrict__ wq,
                     const float* __restrict__ wk, float* __restrict__ fs,
                     float* __restrict__ g, short* __restrict__ xbf,
                     uint* __restrict__ fmxu, uint* __restrict__ fmnu) {
    int b = blockIdx.y;
    int t = threadIdx.x;
    int nl = (t & 31) * 2;
    int cg = t >> 5;                     // 0..7
    int n = blockIdx.x * 64 + nl;
    const float* xb = x + (size_t)b * CQ * NQ + n;
    uint* xo = (uint*)(xbf + (size_t)b * CQ * NQ + n);
    float f0 = 0.f, f1 = 0.f, g0 = 0.f, g1 = 0.f;
    int c0 = cg * 32;
#pragma unroll 8
    for (int c = c0; c < c0 + 32; ++c) {
        float2 v = *(const float2*)&xb[(size_t)c * NQ];
        f0 = fmaf(wq[c], v.x, f0);
        f1 = fmaf(wq[c], v.y, f1);
        g0 = fmaf(wk[c], v.x, g0);
        g1 = fmaf(wk[c], v.y, g1);
        uint p = (uint)(unsigned short)f2bf(v.x) | ((uint)(unsigned short)f2bf(v.y) << 16);
        xo[c * (NQ / 2)] = p;
    }
    __shared__ float sf[8][64], sg2[8][64];
    sf[cg][nl] = f0;  sf[cg][nl + 1] = f1;
    sg2[cg][nl] = g0; sg2[cg][nl + 1] = g1;
    __syncthreads();
    if (t < 64) {
        float f = 0.f, gg = 0.f;
#pragma unroll
        for (int i = 0; i < 8; ++i) { f += sf[i][t]; gg += sg2[i][t]; }
        f *= LOG2E;
        fs[b * NQ + blockIdx.x * 64 + t] = f;
        g[b * NQ + blockIdx.x * 64 + t]  = gg;
        float mx = f, mn = f;
#pragma unroll
        for (int off = 32; off; off >>= 1) {
            mx = fmaxf(mx, __shfl_xor(mx, off));
            mn = fminf(mn, __shfl_xor(mn, off));
        }
        if (t == 0) {
            atomicMax(&fmxu[b], fkey(mx));
            atomicMin(&fmnu[b], fkey(mn));
        }
    }
}

// LDS map (bytes):
//   [0, 64K)      : two 32KB pair-buffers (2 chunks of 256c x 32n bf16, q-swizzled)
//   [0, 128K)     : post-loop f32 partial-merge (8 pairs x 16KB)
//   [0, 64K)      : post-merge y_lds (128m x 512B, XOR-swizzled)
//   [128K, 144K)  : f_lds (4096 f32)
//   [144K, 146K)  : zbuf (512 f32)
#define FLDS_OFF 131072
#define ZBUF_OFF 147456
#define SMEM_BYTES 149504

// -------- K2 fused: y[c][m] = sum_n x[c][n] e[n,m];  o = (1-g)*wv*(y/Z) + g*x --------
// 1024 thr, 16 waves (4/SIMD): ws = w&1 (chunk parity), wm = (w>>1)&3 (m-quarter),
// wc = w>>3 (c-half). Block tile 256c x 128m; wave tile 128c x 32m (jc=8 x jm=2,
// acc = 64 VGPR to fit the 128-VGPR cap at 4 waves/SIMD). Superstep = 2 chunks,
// hoisted incremental stage pointers, one __syncthreads per superstep.
__global__ void __launch_bounds__(1024, 4) k_attn(
    const short* __restrict__ xbf, const float* __restrict__ fsp,
    const float* __restrict__ gp, const uint* __restrict__ fmxu,
    const uint* __restrict__ fmnu, const float* __restrict__ wv,
    const float* __restrict__ x, const float* __restrict__ gamma,
    float* __restrict__ out) {
    __shared__ __align__(16) char smem[SMEM_BYTES];

    int bid = blockIdx.x;
    int b = bid & 7;            // batch -> XCD affinity (2MB xbf slice per XCD L2)
    int mblk = bid >> 3;        // 0..31
    int m0 = mblk * MT;
    int tid = threadIdx.x;
    int l = tid & 63;
    int w = tid >> 6;           // 0..15
    int ws = w & 1;             // chunk within pair
    int wm = (w >> 1) & 3;      // m-quarter
    int wc = w >> 3;            // c-half
    int q = l >> 4;             // k-slot
    int cr = l & 15;            // A-row / B-col within frag
    int qp16 = (q ^ ((cr >> 1) & 3)) * 16;   // swizzled 16B slot for A-reads

    const short* xb = xbf + (size_t)b * CQ * NQ;
    const float* fb = fsp + b * NQ;

    // hoisted staging addresses: dest fixed per lane, src advances +64/superstep
    int dst0 = tid * 16;                 // covers chunk-half 0 (16KB)
    int dst1 = tid * 16 + 16384;         // chunk-half 1
    int srow = tid >> 2;                 // 0..255 (c row)
    int slq = (tid & 3) ^ ((srow >> 1) & 3);  // q-swizzle pre-applied on global src
    const short* src0 = xb + (size_t)srow * NQ + slq * 8;
    const short* src1 = src0 + 32;

    // ---- prolog: stage f (16KB) + pair 0 ----
    __builtin_amdgcn_global_load_lds(
        (const __attribute__((address_space(1))) void*)(fb + tid * 4),
        (__attribute__((address_space(3))) void*)(smem + FLDS_OFF + tid * 16), 16, 0, 0);
    __builtin_amdgcn_global_load_lds(
        (const __attribute__((address_space(1))) void*)src0,
        (__attribute__((address_space(3))) void*)(smem + dst0), 16, 0, 0);
    __builtin_amdgcn_global_load_lds(
        (const __attribute__((address_space(1))) void*)src1,
        (__attribute__((address_space(3))) void*)(smem + dst1), 16, 0, 0);
    src0 += 64;
    src1 += 64;

    float fmx = fdec(fmxu[b]), fmn = fdec(fmnu[b]);
    const float* gb = gp + b * NQ;
    float gj[2], nM[2], zac[2];
#pragma unroll
    for (int jm = 0; jm < 2; ++jm) {
        float gv = gb[m0 + wm * 32 + jm * 16 + cr];
        gj[jm] = gv;
        nM[jm] = -((gv >= 0.f) ? gv * fmx : gv * fmn);
        zac[jm] = 0.f;
    }

    f32x4 acc[8][2];
#pragma unroll
    for (int jc = 0; jc < 8; ++jc)
#pragma unroll
        for (int jm = 0; jm < 2; ++jm) acc[jc][jm] = (f32x4){0.f, 0.f, 0.f, 0.f};

    __syncthreads();   // f + pair0 ready

    for (int s = 0; s < NSUP; ++s) {
        if (s < NSUP - 1) {   // stage pair s+1 into buffer (s+1)&1
            char* nbuf = smem + ((s + 1) & 1) * 32768;
            __builtin_amdgcn_global_load_lds(
                (const __attribute__((address_space(1))) void*)src0,
                (__attribute__((address_space(3))) void*)(nbuf + dst0), 16, 0, 0);
            __builtin_amdgcn_global_load_lds(
                (const __attribute__((address_space(1))) void*)src1,
                (__attribute__((address_space(3))) void*)(nbuf + dst1), 16, 0, 0);
            src0 += 64;
            src1 += 64;
        }
        int chunk = 2 * s + ws;
        const char* cbuf = smem + (s & 1) * 32768 + ws * 16384;
        const float* fls = (const float*)(smem + FLDS_OFF) + chunk * 32;
        float4 fqa = *(const float4*)(fls + q * 8);
        float4 fqb = *(const float4*)(fls + q * 8 + 4);
        float fq[8] = {fqa.x, fqa.y, fqa.z, fqa.w, fqb.x, fqb.y, fqb.z, fqb.w};
        s16x8 bv[2];
#pragma unroll
        for (int jm = 0; jm < 2; ++jm) {
            float z = zac[jm];
#pragma unroll
            for (int i = 0; i < 8; ++i) {
                float e = __builtin_amdgcn_exp2f(fmaf(fq[i], gj[jm], nM[jm]));
                z += e;
                bv[jm][i] = f2bf(e);
            }
            zac[jm] = z;
        }
#pragma unroll
        for (int jc = 0; jc < 8; ++jc) {
            s16x8 av = *(const s16x8*)(cbuf + (wc * 128 + jc * 16 + cr) * 64 + qp16);
            acc[jc][0] = __builtin_amdgcn_mfma_f32_16x16x32_bf16(av, bv[0], acc[jc][0], 0, 0, 0);
            acc[jc][1] = __builtin_amdgcn_mfma_f32_16x16x32_bf16(av, bv[1], acc[jc][1], 0, 0, 0);
        }
        __syncthreads();   // pair s+1 landed; everyone done with buf (s&1)
    }

    // ---- Z: butterfly over k-slots, then exchange across ws-partner ----
    float zf[2];
#pragma unroll
    for (int jm = 0; jm < 2; ++jm) {
        float z = zac[jm];
        z += __shfl_xor(z, 16);
        z += __shfl_xor(z, 32);
        zf[jm] = z;
    }
    float* zb = (float*)(smem + ZBUF_OFF);
    if (q == 0) {
#pragma unroll
        for (int jm = 0; jm < 2; ++jm) zb[w * 32 + jm * 16 + cr] = zf[jm];
    }
    __syncthreads();
#pragma unroll
    for (int jm = 0; jm < 2; ++jm) zf[jm] += zb[(w ^ 1) * 32 + jm * 16 + cr];

    // ---- acc merge across ws pairs: ws1 -> LDS (f32, 8 x 16KB), ws0 adds ----
    {
        int p = wc * 4 + wm;
        float* mrg = (float*)(smem + p * 16384);
        if (ws == 1) {
#pragma unroll
            for (int jc = 0; jc < 8; ++jc)
#pragma unroll
                for (int jm = 0; jm < 2; ++jm)
                    *(f32x4*)(mrg + ((jc * 2 + jm) * 64 + l) * 4) = acc[jc][jm];
        }
        __syncthreads();
        if (ws == 0) {
#pragma unroll
            for (int jc = 0; jc < 8; ++jc)
#pragma unroll
                for (int jm = 0; jm < 2; ++jm) {
                    f32x4 o = *(const f32x4*)(mrg + ((jc * 2 + jm) * 64 + l) * 4);
                    acc[jc][jm] += o;
                }
        }
        __syncthreads();
    }

    // ---- y_norm -> LDS (ws0 waves): y_lds[m][c] bf16, 512B rows, XOR-swizzled ----
    if (ws == 0) {
        float rzl[2];
#pragma unroll
        for (int jm = 0; jm < 2; ++jm) rzl[jm] = 1.0f / zf[jm];
#pragma unroll
        for (int jc = 0; jc < 8; ++jc) {
#pragma unroll
            for (int jm = 0; jm < 2; ++jm) {
                int mloc = wm * 32 + jm * 16 + cr;
                int cb = (wc * 256 + jc * 32 + q * 8) ^ ((mloc & 7) << 4);
                s16x4 v;
#pragma unroll
                for (int r = 0; r < 4; ++r) v[r] = f2bf(acc[jc][jm][r] * rzl[jm]);
                *(s16x4*)(smem + mloc * 512 + cb) = v;
            }
        }
    }
    __syncthreads();

    // ---- GEMM2: o[c_out][m] = wv[c_out][:] . y_norm[:][m], K=256 (16 waves) ----
    int co0 = w * 16;
    f32x4 acc2[8];
#pragma unroll
    for (int jm2 = 0; jm2 < 8; ++jm2) acc2[jm2] = (f32x4){0.f, 0.f, 0.f, 0.f};

#pragma unroll 2
    for (int ks = 0; ks < 8; ++ks) {
        s16x8 a2;
        {
            const float* wr = wv + (size_t)(co0 + cr) * CQ + ks * 32 + q * 8;
            float4 wa = ld4(wr);
            float4 wb = ld4(wr + 4);
            a2[0] = f2bf(wa.x); a2[1] = f2bf(wa.y);
            a2[2] = f2bf(wa.z); a2[3] = f2bf(wa.w);
            a2[4] = f2bf(wb.x); a2[5] = f2bf(wb.y);
            a2[6] = f2bf(wb.z); a2[7] = f2bf(wb.w);
        }
#pragma unroll
        for (int jm2 = 0; jm2 < 8; ++jm2) {
            int mloc = jm2 * 16 + cr;
            s16x8 b2 = *(const s16x8*)(smem + mloc * 512 + ((ks * 64 + q * 16) ^ ((mloc & 7) << 4)));
            acc2[jm2] = __builtin_amdgcn_mfma_f32_16x16x32_bf16(a2, b2, acc2[jm2], 0, 0, 0);
        }
    }

    // ---- epilogue ----
    float gam = gamma[0];
    float omg = 1.f - gam;
    if (gam != 0.f) {
#pragma unroll
        for (int jm2 = 0; jm2 < 8; ++jm2)
#pragma unroll
            for (int r = 0; r < 4; ++r) {
                int c_out = co0 + q * 4 + r;
                size_t idx = ((size_t)b * CQ + c_out) * NQ + m0 + jm2 * 16 + cr;
                __builtin_nontemporal_store(
                    fmaf(gam, x[idx], acc2[jm2][r] * omg), out + idx);
            }
    } else {
#pragma unroll
        for (int jm2 = 0; jm2 < 8; ++jm2)
#pragma unroll
            for (int r = 0; r < 4; ++r) {
                int c_out = co0 + q * 4 + r;
                size_t idx = ((size_t)b * CQ + c_out) * NQ + m0 + jm2 * 16 + cr;
                __builtin_nontemporal_store(acc2[jm2][r] * omg, out + idx);
            }
    }
}

extern "C" void kernel_launch(void* const* d_in, const int* in_sizes, int n_in,
                              void* d_out, int out_size, void* d_ws, size_t ws_size,
                              hipStream_t stream) {
    const float* x     = (const float*)d_in[0];
    const float* wq    = (const float*)d_in[1];
    const float* wk    = (const float*)d_in[2];
    const float* wv    = (const float*)d_in[3];
    const float* gamma = (const float*)d_in[4];
    float* out = (float*)d_out;

    // ws (floats): fs[B*N] | g[B*N] | fmxu[8]+fmnu[8] (uint) | pad -> xbf (bf16) [B*C*N]
    float* ws  = (float*)d_ws;
    float* fs  = ws;
    float* g   = ws + BQ * NQ;
    uint* fmxu = (uint*)(ws + 2 * BQ * NQ);
    uint* fmnu = fmxu + 8;
    short* xbf = (short*)(ws + 2 * BQ * NQ + 64);

    hipMemsetAsync(fmxu, 0x00, 32, stream);   // lowest key
    hipMemsetAsync(fmnu, 0xFF, 32, stream);   // highest key
    hipLaunchKernelGGL(k_fg, dim3(NQ / 64, BQ), dim3(256), 0, stream,
                       x, wq, wk, fs, g, xbf, fmxu, fmnu);
    hipLaunchKernelGGL(k_attn, dim3(BQ * (NQ / MT)), dim3(1024), 0, stream,
                       xbf, fs, g, fmxu, fmnu, wv, x, gamma, out);
}